// Round 12
// baseline (92.619 us; speedup 1.0000x reference)
//
#include <hip/hip_runtime.h>
#include <math.h>

#define N_NODES 50000
#define N_EDGES 800000
#define HIDDEN  256
#define OUT_DIM 10
#define LN_EPS  1e-5f

#define NP    25                   // node partitions
#define PART  2000                 // nodes per partition (25*2000 = 50000 exact)
#define ES    10                   // edge slices
#define EPSE  (N_EDGES / ES)       // 80000 edges per slice
#define EPSE4 (EPSE / 4)           // 20000 int4 per slice
#define NH2   (N_NODES / 2)        // 25000 node pairs
#define NPB   64                   // nodes per ln block
#define LNB   ((N_NODES + NPB - 1) / NPB)   // 782 blocks

// ---------------- D1: histogram + fused dinv/y via per-partition ticket ----
// Block (slice s, part p): LDS hist of its node range over its edge slice,
// packed u16-pair partial store. The LAST of the 10 slice-blocks for a
// partition (ticket) reduces the 10 partials -> dinv, y = dinv*x.
__global__ __launch_bounds__(1024) void hist_dinvy_kernel(
    const int4* __restrict__ dst4, const float4* __restrict__ nf4,
    unsigned* __restrict__ degp32, float2* __restrict__ dinv2,
    float4* __restrict__ y4, unsigned* __restrict__ ticketA,
    const float4* __restrict__ Wh4, const float4* __restrict__ Wo4)
{
    __shared__ unsigned hist[PART];          // 8 KB
    __shared__ unsigned oldv;
    const int tid = threadIdx.x;
    const int s = blockIdx.x, p = blockIdx.y;
    const int gb = p * ES + s;

    // L3-warm MLP weights for the D3 tail (keep-alive, no DCE)
    if (gb < 17) {
        const int idx = gb * 1024 + tid;
        if (idx < 16384) {
            const float4 v = Wh4[idx];
            asm volatile("" :: "v"(v.x + v.y + v.z + v.w));
        } else if (idx < 17024) {
            const float4 v = Wo4[idx - 16384];
            asm volatile("" :: "v"(v.x + v.y + v.z + v.w));
        }
    }

    for (int i = tid; i < PART; i += 1024) hist[i] = 0u;
    __syncthreads();

    const int base = p * PART;
    const int b0 = s * EPSE4;
    for (int i = tid; i < EPSE4; i += 1024) {
        const int4 d = dst4[b0 + i];
        unsigned r;
        r = (unsigned)(d.x - base); if (r < PART) atomicAdd(&hist[r], 1u);
        r = (unsigned)(d.y - base); if (r < PART) atomicAdd(&hist[r], 1u);
        r = (unsigned)(d.z - base); if (r < PART) atomicAdd(&hist[r], 1u);
        r = (unsigned)(d.w - base); if (r < PART) atomicAdd(&hist[r], 1u);
    }
    __syncthreads();

    unsigned* outp = degp32 + (size_t)s * NH2 + base / 2;
    for (int i = tid; i < PART / 2; i += 1024)
        outp[i] = (hist[2 * i] & 0xFFFFu) | (hist[2 * i + 1] << 16);
    __syncthreads();

    if (tid == 0)
        oldv = __hip_atomic_fetch_add(&ticketA[p * 16], 1u, __ATOMIC_ACQ_REL,
                                      __HIP_MEMORY_SCOPE_AGENT);
    __syncthreads();
    if (oldv != ES - 1) return;

    // tail: reduce 10 slice partials for this partition -> dinv, y
    if (tid < PART / 2) {
        const int i = base / 2 + tid;           // pair index
        unsigned s0 = 0, s1 = 0;
        #pragma unroll
        for (int ss = 0; ss < ES; ++ss) {
            const unsigned d = degp32[(size_t)ss * NH2 + i];
            s0 += d & 0xFFFFu;
            s1 += d >> 16;
        }
        const float di0 = rsqrtf((float)s0 + 1.0f);
        const float di1 = rsqrtf((float)s1 + 1.0f);
        dinv2[i] = make_float2(di0, di1);
        const float4 x = nf4[i];
        y4[i] = make_float4(di0 * x.x, di0 * x.y, di1 * x.z, di1 * x.w);
    }
}

// ---------------- D2: scatter + fused dense-T reduce via ticket ------------
// Block (s,p): LDS accumulate y[src] for its node range over its slice;
// plain Tpart store. Last-of-10 block per partition sums the 10 slices ->
// dense T (plain stores, no atomics, T never memset).
__global__ __launch_bounds__(1024) void scatter_kernel(
    const int4* __restrict__ src4, const int4* __restrict__ dst4,
    const float2* __restrict__ y, float2* __restrict__ Tpart2,
    float2* __restrict__ T2, unsigned* __restrict__ ticketB)
{
    __shared__ float Tl[2 * PART];           // 16 KB
    __shared__ unsigned oldv;
    const int tid = threadIdx.x;
    const int s = blockIdx.x, p = blockIdx.y;

    for (int i = tid; i < 2 * PART; i += 1024) Tl[i] = 0.f;
    __syncthreads();

    const int base = p * PART;
    const int b0 = s * EPSE4;
    for (int i = tid; i < EPSE4; i += 1024) {
        const int4 d = dst4[b0 + i];
        const int4 sv = src4[b0 + i];
        unsigned r;
        r = (unsigned)(d.x - base);
        if (r < PART) { const float2 ys = y[sv.x]; atomicAdd(&Tl[2*r], ys.x); atomicAdd(&Tl[2*r+1], ys.y); }
        r = (unsigned)(d.y - base);
        if (r < PART) { const float2 ys = y[sv.y]; atomicAdd(&Tl[2*r], ys.x); atomicAdd(&Tl[2*r+1], ys.y); }
        r = (unsigned)(d.z - base);
        if (r < PART) { const float2 ys = y[sv.z]; atomicAdd(&Tl[2*r], ys.x); atomicAdd(&Tl[2*r+1], ys.y); }
        r = (unsigned)(d.w - base);
        if (r < PART) { const float2 ys = y[sv.w]; atomicAdd(&Tl[2*r], ys.x); atomicAdd(&Tl[2*r+1], ys.y); }
    }
    __syncthreads();

    {
        float2* outp = Tpart2 + (size_t)s * N_NODES + base;
        const float2* Tl2 = (const float2*)Tl;
        for (int i = tid; i < PART; i += 1024) outp[i] = Tl2[i];
    }
    __syncthreads();

    if (tid == 0)
        oldv = __hip_atomic_fetch_add(&ticketB[p * 16], 1u, __ATOMIC_ACQ_REL,
                                      __HIP_MEMORY_SCOPE_AGENT);
    __syncthreads();
    if (oldv != ES - 1) return;

    // tail: dense T for this partition (plain stores)
    for (int i = tid; i < PART; i += 1024) {
        float ax = 0.f, ay = 0.f;
        #pragma unroll
        for (int ss = 0; ss < ES; ++ss) {
            const float2 v = Tpart2[(size_t)ss * N_NODES + base + i];
            ax += v.x; ay += v.y;
        }
        T2[base + i] = make_float2(ax, ay);
    }
}

// ---- D3: dense-T LN (scalar-load pass1) + 8-way atomic pool + MLP tail ----
__global__ __launch_bounds__(256) void ln_pool_mlp_kernel(
    const float2* __restrict__ T2,
    const float2* __restrict__ y,
    const float* __restrict__ dinv,
    const float* __restrict__ Wg, const float* __restrict__ bg,
    const float* __restrict__ gamma, const float* __restrict__ beta,
    const float* __restrict__ Wh, const float* __restrict__ bh,
    const float* __restrict__ Wo, const float* __restrict__ bo,
    float* __restrict__ pooled8,
    unsigned* __restrict__ ticket,
    float* __restrict__ out)
{
    const int tid  = threadIdx.x;
    const int bid  = blockIdx.x;
    const int n0   = bid * NPB;
    const int lane = tid & 63;
    const int wv   = tid >> 6;               // 4 waves == 4 j-groups

    __shared__ float4 nd[NPB];               // (s0, s1, r, r*mu)
    __shared__ float  ps[4][NPB];
    __shared__ float  qs[4][NPB];
    __shared__ float  red[4][HIDDEN];
    __shared__ float  pz[HIDDEN], zz[HIDDEN];
    __shared__ float  lgp[OUT_DIM][16], lg[OUT_DIM];
    __shared__ int    is_last;

    if (tid < NPB) {
        const int n = n0 + tid;
        float s0 = 0.f, s1 = 0.f;
        if (n < N_NODES) {
            const float di = dinv[n];
            const float2 yn = y[n];
            const float2 t  = T2[n];
            s0 = di * (t.x + yn.x);
            s1 = di * (t.y + yn.y);
        }
        nd[tid] = make_float4(s0, s1, 0.f, 0.f);
    }
    __syncthreads();

    // pass 1: lane = node, wave = 64-col group; W via wave-uniform scalar loads
    {
        const int jgu = __builtin_amdgcn_readfirstlane(wv);
        const float* w0p = Wg + jgu * 64;
        const float* w1p = Wg + HIDDEN + jgu * 64;
        const float* bgp = bg + jgu * 64;
        const float4 d = nd[lane];
        float sumA = 0.f, sumB = 0.f, sqA = 0.f, sqB = 0.f;
        #pragma unroll 8
        for (int j = 0; j < 64; j += 2) {
            const float va = fmaxf(fmaf(d.y, w1p[j],     fmaf(d.x, w0p[j],     bgp[j])),     0.f);
            const float vb = fmaxf(fmaf(d.y, w1p[j + 1], fmaf(d.x, w0p[j + 1], bgp[j + 1])), 0.f);
            sumA += va; sqA = fmaf(va, va, sqA);
            sumB += vb; sqB = fmaf(vb, vb, sqB);
        }
        ps[wv][lane] = sumA + sumB;
        qs[wv][lane] = sqA + sqB;
    }
    __syncthreads();

    if (tid < NPB) {
        const float sum = ps[0][tid] + ps[1][tid] + ps[2][tid] + ps[3][tid];
        const float sq  = qs[0][tid] + qs[1][tid] + qs[2][tid] + qs[3][tid];
        const float mu  = sum * (1.0f / HIDDEN);
        const float var = sq * (1.0f / HIDDEN) - mu * mu;
        float r = rsqrtf(var + LN_EPS);
        if (n0 + tid >= N_NODES) r = 0.f;
        const float4 d = nd[tid];
        nd[tid] = make_float4(d.x, d.y, r, r * mu);
    }
    __syncthreads();

    // pass 2: wave = 16 nodes, lane = 4 columns
    {
        const float4 w0  = *reinterpret_cast<const float4*>(&Wg[lane * 4]);
        const float4 w1  = *reinterpret_cast<const float4*>(&Wg[HIDDEN + lane * 4]);
        const float4 bgv = *reinterpret_cast<const float4*>(&bg[lane * 4]);

        float a0 = 0.f, a1 = 0.f, a2 = 0.f, a3 = 0.f;
        #pragma unroll
        for (int k = 0; k < 16; ++k) {
            const float4 d = nd[wv * 16 + k];    // broadcast read
            const float v0 = fmaxf(fmaf(d.y, w1.x, fmaf(d.x, w0.x, bgv.x)), 0.f);
            const float v1 = fmaxf(fmaf(d.y, w1.y, fmaf(d.x, w0.y, bgv.y)), 0.f);
            const float v2 = fmaxf(fmaf(d.y, w1.z, fmaf(d.x, w0.z, bgv.z)), 0.f);
            const float v3 = fmaxf(fmaf(d.y, w1.w, fmaf(d.x, w0.w, bgv.w)), 0.f);
            a0 += fmaf(d.z, v0, -d.w);
            a1 += fmaf(d.z, v1, -d.w);
            a2 += fmaf(d.z, v2, -d.w);
            a3 += fmaf(d.z, v3, -d.w);
        }
        red[wv][lane * 4 + 0] = a0;
        red[wv][lane * 4 + 1] = a1;
        red[wv][lane * 4 + 2] = a2;
        red[wv][lane * 4 + 3] = a3;
    }
    __syncthreads();

    atomicAdd(&pooled8[(bid & 7) * HIDDEN + tid],
              red[0][tid] + red[1][tid] + red[2][tid] + red[3][tid]);
    __syncthreads();

    if (tid == 0) {
        const unsigned old = __hip_atomic_fetch_add(ticket, 1u, __ATOMIC_ACQ_REL,
                                                    __HIP_MEMORY_SCOPE_AGENT);
        is_last = (old == (unsigned)(gridDim.x - 1));
    }
    __syncthreads();
    if (!is_last) return;

    {
        float S = 0.f;
        #pragma unroll
        for (int k = 0; k < 8; ++k) S += pooled8[k * HIDDEN + tid];
        pz[tid] = gamma[tid] * S + (float)N_NODES * beta[tid];
    }
    __syncthreads();

    {
        float acc = bh[tid];
        #pragma unroll 8
        for (int k = 0; k < HIDDEN; ++k) acc = fmaf(pz[k], Wh[k * HIDDEN + tid], acc);
        zz[tid] = fmaxf(acc, 0.f);
    }
    __syncthreads();

    if (tid < OUT_DIM * 16) {
        const int o = tid >> 4, kc = tid & 15;
        float acc = 0.f;
        #pragma unroll
        for (int k = kc * 16; k < kc * 16 + 16; ++k)
            acc = fmaf(zz[k], Wo[k * OUT_DIM + o], acc);
        lgp[o][kc] = acc;
    }
    __syncthreads();
    if (tid < OUT_DIM) {
        float t = bo[tid];
        #pragma unroll
        for (int q = 0; q < 16; ++q) t += lgp[tid][q];
        lg[tid] = t;
    }
    __syncthreads();

    if (tid == 0) {
        float m = lg[0];
        for (int k = 1; k < OUT_DIM; ++k) m = fmaxf(m, lg[k]);
        float sum = 0.f;
        for (int k = 0; k < OUT_DIM; ++k) sum += expf(lg[k] - m);
        const float lse = m + logf(sum);
        for (int k = 0; k < OUT_DIM; ++k) out[k] = lg[k] - lse;
    }
}

// ---------------------------------------------------------------- launch ----
extern "C" void kernel_launch(void* const* d_in, const int* in_sizes, int n_in,
                              void* d_out, int out_size, void* d_ws, size_t ws_size,
                              hipStream_t stream) {
    const float* nf    = (const float*)d_in[0];   // [N, 2]
    const int*   ei    = (const int*)  d_in[1];   // [2, E] int32
    const float* Wg    = (const float*)d_in[2];
    const float* bg    = (const float*)d_in[3];
    const float* gamma = (const float*)d_in[4];
    const float* beta  = (const float*)d_in[5];
    const float* Wh    = (const float*)d_in[6];
    const float* bh    = (const float*)d_in[7];
    const float* Wo    = (const float*)d_in[8];
    const float* bo    = (const float*)d_in[9];
    float* out = (float*)d_out;

    const int* srcp = ei;
    const int* dstp = ei + N_EDGES;               // 3.2MB offset: 16B-aligned

    // workspace layout (4B units):
    // ticketA [NP*16] | ticketB [NP*16] | mlp_ticket [16] | pooled8 [8*H]
    // | degp32 [ES*NH2] (1MB) | Tpart2 [ES*N] float2 (4MB) | T [2N] | dinv [N] | y [2N]
    unsigned* ticketA = (unsigned*)d_ws;
    unsigned* ticketB = ticketA + NP * 16;
    unsigned* mlp_ticket = ticketB + NP * 16;
    float* pooled8 = (float*)(mlp_ticket + 16);
    unsigned* degp32 = (unsigned*)(pooled8 + 8 * HIDDEN);
    float* Tpart = (float*)(degp32 + (size_t)ES * NH2);
    float* T     = Tpart + (size_t)ES * 2 * N_NODES;
    float* dinvp = T + 2 * N_NODES;
    float* yp    = dinvp + N_NODES;

    // zero all tickets + pooled8 (poison/replay-safe)
    hipMemsetAsync(d_ws, 0, (size_t)(2 * NP * 16 + 16 + 8 * HIDDEN) * 4, stream);

    dim3 pg(ES, NP);
    hist_dinvy_kernel<<<pg, 1024, 0, stream>>>((const int4*)dstp, (const float4*)nf,
                                               degp32, (float2*)dinvp, (float4*)yp,
                                               ticketA, (const float4*)Wh, (const float4*)Wo);
    scatter_kernel<<<pg, 1024, 0, stream>>>((const int4*)srcp, (const int4*)dstp,
                                            (const float2*)yp, (float2*)Tpart,
                                            (float2*)T, ticketB);
    ln_pool_mlp_kernel<<<LNB, 256, 0, stream>>>((const float2*)T, (const float2*)yp, dinvp,
                                                Wg, bg, gamma, beta, Wh, bh, Wo, bo,
                                                pooled8, mlp_ticket, out);
}